// Round 1
// baseline (289.297 us; speedup 1.0000x reference)
//
#include <hip/hip_runtime.h>
#include <hip/hip_bf16.h>
#include <math.h>

#define B_ 4
#define T_ 2048
#define D_ 1024
#define H_ 16
#define HD_ 64

typedef _Float16 f16x8 __attribute__((ext_vector_type(8)));
typedef _Float16 f16x4 __attribute__((ext_vector_type(4)));
typedef float f32x4 __attribute__((ext_vector_type(4)));

// async global->LDS, 16 B per lane, dest = wave-uniform base + lane*16
__device__ __forceinline__ void gload_lds16(const _Float16* g, _Float16* l) {
    __builtin_amdgcn_global_load_lds(
        (const __attribute__((address_space(1))) void*)g,
        (__attribute__((address_space(3))) void*)l,
        16, 0, 0);
}

// ---------------------------------------------------------------------------
// fp32 -> fp16 cast, 4 elems/thread
// ---------------------------------------------------------------------------
__global__ __launch_bounds__(256) void castf(const float* __restrict__ in,
                                             _Float16* __restrict__ out, int n4) {
    const int i = blockIdx.x * 256 + threadIdx.x;
    if (i < n4) {
        const float4 v = ((const float4*)in)[i];
        f16x4 h = {(_Float16)v.x, (_Float16)v.y, (_Float16)v.z, (_Float16)v.w};
        ((f16x4*)out)[i] = h;
    }
}

// fused 4-weight cast: grid.z selects which weight
__global__ __launch_bounds__(256) void castw(const float* __restrict__ a,
                                             const float* __restrict__ b,
                                             const float* __restrict__ c,
                                             const float* __restrict__ d,
                                             _Float16* __restrict__ oa,
                                             _Float16* __restrict__ ob,
                                             _Float16* __restrict__ oc,
                                             _Float16* __restrict__ od) {
    const int z = blockIdx.z;
    const float* in = (z == 0) ? a : (z == 1 ? b : (z == 2 ? c : d));
    _Float16* out = (z == 0) ? oa : (z == 1 ? ob : (z == 2 ? oc : od));
    const int i = blockIdx.x * 256 + threadIdx.x;
    const float4 v = ((const float4*)in)[i];
    f16x4 h = {(_Float16)v.x, (_Float16)v.y, (_Float16)v.z, (_Float16)v.w};
    ((f16x4*)out)[i] = h;
}

// ---------------------------------------------------------------------------
// Fused QKV GEMM + rmsnorm/rotary epilogue — 256x256 8-phase template
// (T2 swizzle + T3/T4 counted vmcnt + T5 setprio).
// 512 thr = 8 waves (2M x 4N); per-wave C tile 128x64 (one head wide).
// LDS: 2 dbuf x (A 256x64 + B 256x64) f16 = 128 KiB, linear physical layout,
// XOR-swizzled logically: data for logical (row, chunk8) lives at physical
// chunk8 ^ (row&7).  global_load_lds writes linearly -> source pre-swizzled
// (rule #21); ds_read applies the same XOR -> 16-lane column reads become
// 2-way bank aliasing (free).
// Schedule per iter (2 K-tiles, BK=64, buf0=even tile, buf1=odd tile):
//   p1: rdA(m0,buf0)+rdB(n01,buf0)  stage buf1.Bh0<-t(2i+1)   MFMA m0xn01
//   p2: rdA(m1,buf0)                stage buf1.Bh1<-t(2i+1)   MFMA m1xn01
//   p3: rdB(n23,buf0)               stage buf0.Ah0<-t(2i+2)   MFMA m1xn23
//   p4:                             stage buf0.Ah1<-t(2i+2)   MFMA m0xn23  vmcnt(4)
//   p5..p8: mirror on buf1, staging buf0.Bh0/Bh1<-t(2i+2), buf1.Ah0/Ah1<-t(2i+3)
// vmcnt(4) = allow the 2 newest half-tiles (4 loads/thread) in flight; never 0
// in the main loop.  A-halves of the live buffer are last read in p2 (all 8
// a-frags held in regs), B-halves in p3 -> staging slots above are race-free.
// z=0: rms+rotary+0.125*log2e -> qh ; z=1: rms+rotary -> kh ;
// z=2: plain -> vt transposed [b][h][d][T]
// ---------------------------------------------------------------------------

#define PHASE_MID() \
    __builtin_amdgcn_s_barrier(); \
    asm volatile("s_waitcnt lgkmcnt(0)" ::: "memory"); \
    __builtin_amdgcn_sched_barrier(0); \
    __builtin_amdgcn_s_setprio(1)

#define PHASE_END() \
    __builtin_amdgcn_s_setprio(0); \
    __builtin_amdgcn_s_barrier()

#define VM_PHASE_END(N) \
    __builtin_amdgcn_s_setprio(0); \
    __builtin_amdgcn_sched_barrier(0); \
    asm volatile("s_waitcnt vmcnt(" #N ")" ::: "memory"); \
    __builtin_amdgcn_sched_barrier(0); \
    __builtin_amdgcn_s_barrier()

#define LOAD_A(AR, P, MH) { \
    _Pragma("unroll") \
    for (int i_ = 0; i_ < 4; ++i_) { \
        AR[i_][0] = *(const f16x8*)&As[(P) * 16384 + rowA[MH][i_] + c0s]; \
        AR[i_][1] = *(const f16x8*)&As[(P) * 16384 + rowA[MH][i_] + c1s]; \
    } }

#define LOAD_B(P, NH) { \
    _Pragma("unroll") \
    for (int j_ = 0; j_ < 2; ++j_) { \
        bF[j_][0] = *(const f16x8*)&Bs[(P) * 16384 + rowB[2 * (NH) + j_] + c0s]; \
        bF[j_][1] = *(const f16x8*)&Bs[(P) * 16384 + rowB[2 * (NH) + j_] + c1s]; \
    } }

#define MFMA_Q(AR, MB, NH) { \
    _Pragma("unroll") \
    for (int i_ = 0; i_ < 4; ++i_) { \
        _Pragma("unroll") \
        for (int j_ = 0; j_ < 2; ++j_) { \
            f32x4& d_ = acc[(MB) + i_][2 * (NH) + j_]; \
            d_ = __builtin_amdgcn_mfma_f32_16x16x32_f16(AR[i_][0], bF[j_][0], d_, 0, 0, 0); \
            d_ = __builtin_amdgcn_mfma_f32_16x16x32_f16(AR[i_][1], bF[j_][1], d_, 0, 0, 0); \
        } } }

#define STAGE_A(P, T, HH) \
    gload_lds16(Ap + (size_t)(row0 + (HH) * 128 + w8s) * 1024 + (T) * 64 + sch, \
                &As[(P) * 16384 + (HH) * 8192 + (w << 9)]); \
    gload_lds16(Ap + (size_t)(row0 + (HH) * 128 + 64 + w8s) * 1024 + (T) * 64 + sch, \
                &As[(P) * 16384 + (HH) * 8192 + 4096 + (w << 9)])

#define STAGE_B(P, T, HH) \
    gload_lds16(Wp + (size_t)(col0 + (HH) * 128 + w8s) * 1024 + (T) * 64 + sch, \
                &Bs[(P) * 16384 + (HH) * 8192 + (w << 9)]); \
    gload_lds16(Wp + (size_t)(col0 + (HH) * 128 + 64 + w8s) * 1024 + (T) * 64 + sch, \
                &Bs[(P) * 16384 + (HH) * 8192 + 4096 + (w << 9)])

__global__ __launch_bounds__(512, 2) void gemm_qkv(const _Float16* __restrict__ A,
                                                   const _Float16* __restrict__ Wq,
                                                   const _Float16* __restrict__ Wk,
                                                   const _Float16* __restrict__ Wv,
                                                   _Float16* __restrict__ qh,
                                                   _Float16* __restrict__ kh,
                                                   _Float16* __restrict__ vt) {
    const int z = blockIdx.z;
    const _Float16* Wp = (z == 0) ? Wq : (z == 1 ? Wk : Wv);
    const _Float16* Ap = A;
    __shared__ _Float16 As[2 * 16384];   // 2 bufs x 256 rows x 64 cols
    __shared__ _Float16 Bs[2 * 16384];

    const int tid = threadIdx.x;
    const int lane = tid & 63, w = tid >> 6;          // 8 waves
    const int col = lane & 15, quad = lane >> 4;
    const int wr = w >> 2, wc = w & 3;                // 2M x 4N wave grid
    const int row0 = blockIdx.y * 256, col0 = blockIdx.x * 256;

    // staging per-lane constants (pre-swizzled global source, linear LDS dest)
    const int w8s = (w << 3) + (lane >> 3);
    const int sch = (((lane & 7) ^ (lane >> 3)) << 3);

    // ds_read addressing: logical chunk (quad | 4*ks) at physical chunk ^ (row&7)
    const int swz = col & 7;
    const int c0s = ((quad ^ swz) << 3);
    const int c1s = (((quad | 4) ^ swz) << 3);

    int rowA[2][4], rowB[4];
#pragma unroll
    for (int i = 0; i < 4; ++i) {
        rowA[0][i] = (wr * 128 + i * 16 + col) * 64;
        rowA[1][i] = rowA[0][i] + 4096;
        rowB[i]    = (wc * 64 + i * 16 + col) * 64;
    }

    f32x4 acc[8][4];
#pragma unroll
    for (int i = 0; i < 8; ++i)
#pragma unroll
        for (int j = 0; j < 4; ++j) acc[i][j] = (f32x4){0.f, 0.f, 0.f, 0.f};

    f16x8 aF[4][2], aG[4][2], bF[2][2];

    // ---- prologue: tile0 -> buf0 (full), tile1 Ah -> buf1 ----
    STAGE_A(0, 0, 0); STAGE_A(0, 0, 1);
    STAGE_B(0, 0, 0); STAGE_B(0, 0, 1);
    STAGE_A(1, 1, 0); STAGE_A(1, 1, 1);
    __builtin_amdgcn_sched_barrier(0);
    asm volatile("s_waitcnt vmcnt(4)" ::: "memory");
    __builtin_amdgcn_sched_barrier(0);
    __builtin_amdgcn_s_barrier();

    // ---- main loop: 7 iters x 2 K-tiles (tiles 0..13) ----
    for (int it = 0; it < 7; ++it) {
        const int c1 = 2 * it + 1, n0 = 2 * it + 2, n1 = 2 * it + 3;
        // p1
        LOAD_A(aF, 0, 0); LOAD_B(0, 0);
        STAGE_B(1, c1, 0);
        PHASE_MID(); MFMA_Q(aF, 0, 0); PHASE_END();
        // p2
        LOAD_A(aG, 0, 1);
        STAGE_B(1, c1, 1);
        PHASE_MID(); MFMA_Q(aG, 4, 0); PHASE_END();
        // p3
        LOAD_B(0, 1);
        STAGE_A(0, n0, 0);
        PHASE_MID(); MFMA_Q(aG, 4, 1); PHASE_END();
        // p4
        STAGE_A(0, n0, 1);
        PHASE_MID(); MFMA_Q(aF, 0, 1);
        VM_PHASE_END(4);
        // p5
        LOAD_A(aF, 1, 0); LOAD_B(1, 0);
        STAGE_B(0, n0, 0);
        PHASE_MID(); MFMA_Q(aF, 0, 0); PHASE_END();
        // p6
        LOAD_A(aG, 1, 1);
        STAGE_B(0, n0, 1);
        PHASE_MID(); MFMA_Q(aG, 4, 0); PHASE_END();
        // p7
        LOAD_B(1, 1);
        STAGE_A(1, n1, 0);
        PHASE_MID(); MFMA_Q(aG, 4, 1); PHASE_END();
        // p8
        STAGE_A(1, n1, 1);
        PHASE_MID(); MFMA_Q(aF, 0, 1);
        VM_PHASE_END(4);
    }

    // ---- epilogue iter: tiles 14 (buf0), 15 (buf1); only t15.Bh left to stage
    // p1
    LOAD_A(aF, 0, 0); LOAD_B(0, 0);
    STAGE_B(1, 15, 0);
    PHASE_MID(); MFMA_Q(aF, 0, 0); PHASE_END();
    // p2
    LOAD_A(aG, 0, 1);
    STAGE_B(1, 15, 1);
    PHASE_MID(); MFMA_Q(aG, 4, 0); PHASE_END();
    // p3
    LOAD_B(0, 1);
    PHASE_MID(); MFMA_Q(aG, 4, 1); PHASE_END();
    // p4 — drain: everything must have landed before reading buf1
    PHASE_MID(); MFMA_Q(aF, 0, 1);
    VM_PHASE_END(0);
    // p5
    LOAD_A(aF, 1, 0); LOAD_B(1, 0);
    PHASE_MID(); MFMA_Q(aF, 0, 0); PHASE_END();
    // p6
    LOAD_A(aG, 1, 1);
    PHASE_MID(); MFMA_Q(aG, 4, 0); PHASE_END();
    // p7
    LOAD_B(1, 1);
    PHASE_MID(); MFMA_Q(aG, 4, 1); PHASE_END();
    // p8 (no trailing barrier needed; epilogue is reg/global only)
    PHASE_MID(); MFMA_Q(aF, 0, 1);
    __builtin_amdgcn_s_setprio(0);

    // ---- C epilogue ----
    if (z < 2) {
        _Float16* C = (z == 0) ? qh : kh;
        const float qscale = (z == 0) ? 0.18033688011112042f : 1.0f;  // 0.125*log2(e)
        const float fr = exp2f(-10.0f * (float)col * (1.0f / 15.0f));
#pragma unroll
        for (int mi = 0; mi < 8; ++mi) {
            float ssq[4];
#pragma unroll
            for (int r = 0; r < 4; ++r) {
                float t = 0.f;
#pragma unroll
                for (int ni = 0; ni < 4; ++ni) t += acc[mi][ni][r] * acc[mi][ni][r];
                ssq[r] = t;
            }
#pragma unroll
            for (int st = 1; st < 16; st <<= 1)
#pragma unroll
                for (int r = 0; r < 4; ++r) ssq[r] += __shfl_xor(ssq[r], st, 64);
            const int rowb = row0 + wr * 128 + mi * 16 + quad * 4;
#pragma unroll
            for (int r = 0; r < 4; ++r) {
                const float scl = rsqrtf(ssq[r] * (1.0f / 64.0f) + 1e-6f) * qscale;
                const int t = (rowb + r) & (T_ - 1);
                float s, c;
                sincosf((float)t * fr, &s, &c);
                const float x0 = acc[mi][0][r] * scl;
                const float x1 = acc[mi][1][r] * scl;
                const float x2 = acc[mi][2][r] * scl;
                const float x3 = acc[mi][3][r] * scl;
                const float y0 = fmaf(x0, c, x2 * s);
                const float y2 = fmaf(x2, c, -x0 * s);
                const size_t base = (size_t)(rowb + r) * D_ + col0 + wc * 64 + col;
                C[base + 0]  = (_Float16)y0;
                C[base + 16] = (_Float16)x1;
                C[base + 32] = (_Float16)y2;
                C[base + 48] = (_Float16)x3;
            }
        }
    } else {
        const int hh = blockIdx.x * 4 + wc;
#pragma unroll
        for (int mi = 0; mi < 8; ++mi) {
            const int row = row0 + wr * 128 + mi * 16 + quad * 4;
            const int bb = row >> 11;
            const int t0m = row & (T_ - 1);
#pragma unroll
            for (int ni = 0; ni < 4; ++ni) {
                const int d = ni * 16 + col;
                f16x4 pk = {(_Float16)acc[mi][ni][0], (_Float16)acc[mi][ni][1],
                            (_Float16)acc[mi][ni][2], (_Float16)acc[mi][ni][3]};
                *(f16x4*)&vt[((size_t)(bb * H_ + hh) * HD_ + d) * T_ + t0m] = pk;
            }
        }
    }
}

// ---------------------------------------------------------------------------
// WO GEMM: out[M,N] = A[M,K] @ W[N,K]^T, fp16 in, fp32 out. m97 structure.
// ---------------------------------------------------------------------------
__global__ __launch_bounds__(256) void gemm_wo(const _Float16* __restrict__ A,
                                               const _Float16* __restrict__ W,
                                               float* __restrict__ C) {
    constexpr int K = D_, N = D_;
    __shared__ _Float16 As[128 * 32];
    __shared__ _Float16 Bs[128 * 32];
    const int tid = threadIdx.x;
    const int lane = tid & 63, w = tid >> 6;
    const int col = lane & 15, quad = lane >> 4;
    const int wm = w >> 1, wn = w & 1;
    const int row0 = blockIdx.y * 128, col0 = blockIdx.x * 128;
    const int sr = lane >> 2, sc = (lane & 3) * 8;

    f32x4 acc[4][4];
#pragma unroll
    for (int i = 0; i < 4; ++i)
#pragma unroll
        for (int j = 0; j < 4; ++j) acc[i][j] = (f32x4){0.f, 0.f, 0.f, 0.f};

    for (int kt = 0; kt < K / 32; ++kt) {
        const int k0 = kt * 32;
#pragma unroll
        for (int it = 0; it < 2; ++it) {
            const int rb = it * 64 + w * 16;
            gload_lds16(A + (size_t)(row0 + rb + sr) * K + k0 + sc, As + rb * 32);
            gload_lds16(W + (size_t)(col0 + rb + sr) * K + k0 + sc, Bs + rb * 32);
        }
        __syncthreads();
        f16x8 af[4], bf[4];
#pragma unroll
        for (int i = 0; i < 4; ++i) {
            af[i] = *(const f16x8*)&As[(wm * 64 + i * 16 + col) * 32 + quad * 8];
            bf[i] = *(const f16x8*)&Bs[(wn * 64 + i * 16 + col) * 32 + quad * 8];
        }
#pragma unroll
        for (int mi = 0; mi < 4; ++mi)
#pragma unroll
            for (int ni = 0; ni < 4; ++ni)
                acc[mi][ni] = __builtin_amdgcn_mfma_f32_16x16x32_f16(af[mi], bf[ni],
                                                                     acc[mi][ni], 0, 0, 0);
        __syncthreads();
    }
#pragma unroll
    for (int mi = 0; mi < 4; ++mi)
#pragma unroll
        for (int ni = 0; ni < 4; ++ni)
#pragma unroll
            for (int r = 0; r < 4; ++r)
                C[(size_t)(row0 + wm * 64 + mi * 16 + quad * 4 + r) * N +
                  col0 + wn * 64 + ni * 16 + col] = acc[mi][ni][r];
}

// ---------------------------------------------------------------------------
// MFMA flash attention (fp16 in/out). 512 thr = 8 waves, 128 q per block,
// wave w owns q rows [q0+16w, q0+16w+16). K-tiles of 64 keys.
// ---------------------------------------------------------------------------
#define LDP 88

__global__ __launch_bounds__(512) void flash_mfma(const _Float16* __restrict__ qh,
                                                  const _Float16* __restrict__ kh,
                                                  const _Float16* __restrict__ vt,
                                                  _Float16* __restrict__ o) {
    __shared__ _Float16 Kl[64 * 64];
    __shared__ _Float16 Vl[64 * 64];
    __shared__ _Float16 Pl[8][16 * LDP];
    const int tid = threadIdx.x;
    const int lane = tid & 63, w = tid >> 6;           // w in [0,8)
    const int col = lane & 15, quad = lane >> 4;
    const int bh = blockIdx.x, b = bh >> 4, h = bh & 15;
    const int srow = lane >> 3;                        // row-in-8 for staging
    const int schunk = (lane & 7) ^ srow;              // global-side swizzle
    const int sw = col & 7;                            // read-side swizzle key

    for (int phase = 0; phase < 2; ++phase) {
        const int qt = (phase == 0) ? (int)blockIdx.y : (15 - (int)blockIdx.y);
        const int q0 = qt * 128;

        // Q as B-operand: lane holds Q[q=q0+16w+col][d = quad*8+j (+32)]
        const int tq = q0 + w * 16 + col;
        const _Float16* qp = qh + ((size_t)(b * T_ + tq) * H_ + h) * HD_ + quad * 8;
        const f16x8 qB0 = *(const f16x8*)(qp);
        const f16x8 qB1 = *(const f16x8*)(qp + 32);

        f32x4 oa[4];
#pragma unroll
        for (int i = 0; i < 4; ++i) oa[i] = (f32x4){0.f, 0.f, 0.f, 0.f};
        float l_ = 0.f;  // per-lane partial denom for q = col

        const int nkt = 2 * qt + 2;
        for (int kt = 0; kt < nkt; ++kt) {
            const int k0 = kt * 64;
            // ---- stage K[key][d], Vt[d][key]: 512 thr x 16 B = full tile ----
            {
                const int r = w * 8 + srow;
                gload_lds16(kh + ((size_t)(b * T_ + k0 + r) * H_ + h) * HD_ + schunk * 8,
                            Kl + (w * 8) * 64);
                gload_lds16(vt + ((size_t)(b * H_ + h) * HD_ + r) * T_ + k0 + schunk * 8,
                            Vl + (w * 8) * 64);
            }
            __syncthreads();

            // ---- S^T[key][q]: A = K rows, B = Q (in regs) ----
            f32x4 s[4];
#pragma unroll
            for (int tn = 0; tn < 4; ++tn) {
                const _Float16* kp = &Kl[(tn * 16 + col) * 64];
                const f16x8 kA0 = *(const f16x8*)(kp + ((quad ^ sw) << 3));
                const f16x8 kA1 = *(const f16x8*)(kp + (((quad | 4) ^ sw) << 3));
                f32x4 a = (f32x4){0.f, 0.f, 0.f, 0.f};
                a = __builtin_amdgcn_mfma_f32_16x16x32_f16(kA0, qB0, a, 0, 0, 0);
                a = __builtin_amdgcn_mfma_f32_16x16x32_f16(kA1, qB1, a, 0, 0, 0);
                s[tn] = a;
            }

            // ---- causal mask: any key in tile beyond this wave's q rows ----
            if (k0 + 63 > q0 + w * 16) {
                const int qq = q0 + w * 16 + col;
#pragma unroll
                for (int tn = 0; tn < 4; ++tn)
#pragma unroll
                    for (int r = 0; r < 4; ++r) {
                        const int key = k0 + tn * 16 + quad * 4 + r;
                        if (key > qq) s[tn][r] = -1e30f;
                    }
            }

            // ---- p = exp2(s); l accumulate; packed P store (4x b64) ----
#pragma unroll
            for (int tn = 0; tn < 4; ++tn) {
                f16x4 pk;
#pragma unroll
                for (int r = 0; r < 4; ++r) {
                    const float p = exp2f(s[tn][r]);
                    l_ += p;
                    pk[r] = (_Float16)p;
                }
                *(f16x4*)&Pl[w][col * LDP + tn * 16 + quad * 4] = pk;
            }

            // ---- O[q][d] += P @ V (Pl[w] wave-private, no barrier) ----
            const f16x8 pA0 = *(const f16x8*)&Pl[w][col * LDP + quad * 8];
            const f16x8 pA1 = *(const f16x8*)&Pl[w][col * LDP + quad * 8 + 32];
#pragma unroll
            for (int tn = 0; tn < 4; ++tn) {
                const _Float16* vp = &Vl[(tn * 16 + col) * 64];
                const f16x8 vB0 = *(const f16x8*)(vp + ((quad ^ sw) << 3));
                const f16x8 vB1 = *(const f16x8*)(vp + (((quad | 4) ^ sw) << 3));
                oa[tn] = __builtin_amdgcn_mfma_f32_16x16x32_f16(pA0, vB0, oa[tn], 0, 0, 0);
                oa[tn] = __builtin_amdgcn_mfma_f32_16x16x32_f16(pA1, vB1, oa[tn], 0, 0, 0);
            }
            __syncthreads();
        }

        // ---- finish l (sum quads), redistribute to O rows, write ----
        l_ += __shfl_xor(l_, 16, 64);
        l_ += __shfl_xor(l_, 32, 64);
        const float linv = 1.0f / l_;
        float inv[4];
#pragma unroll
        for (int r = 0; r < 4; ++r) inv[r] = __shfl(linv, quad * 4 + r, 64);
#pragma unroll
        for (int tn = 0; tn < 4; ++tn)
#pragma unroll
            for (int r = 0; r < 4; ++r)
                o[((size_t)(b * T_ + q0 + w * 16 + quad * 4 + r) * H_ + h) * HD_ + tn * 16 + col] =
                    (_Float16)(oa[tn][r] * inv[r]);
    }
}

// ---------------------------------------------------------------------------
extern "C" void kernel_launch(void* const* d_in, const int* in_sizes, int n_in,
                              void* d_out, int out_size, void* d_ws, size_t ws_size,
                              hipStream_t stream) {
    const float* x  = (const float*)d_in[0];
    const float* wq = (const float*)d_in[1];
    const float* wk = (const float*)d_in[2];
    const float* wv = (const float*)d_in[3];
    const float* wo = (const float*)d_in[4];
    float* out = (float*)d_out;

    const size_t NE = (size_t)B_ * T_ * D_;   // 8,388,608
    const size_t WE = (size_t)D_ * D_;        // 1,048,576
    _Float16* xh  = (_Float16*)d_ws;
    _Float16* qh  = xh + NE;
    _Float16* kh  = qh + NE;
    _Float16* vth = kh + NE;
    _Float16* oh  = vth + NE;
    _Float16* wqh = oh + NE;
    _Float16* wkh = wqh + WE;
    _Float16* wvh = wkh + WE;
    _Float16* woh = wvh + WE;

    castf<<<NE / 1024, 256, 0, stream>>>(x, xh, (int)(NE / 4));
    castw<<<dim3(WE / 1024, 1, 4), 256, 0, stream>>>(wq, wk, wv, wo,
                                                     wqh, wkh, wvh, woh);

    gemm_qkv<<<dim3(D_ / 256, (B_ * T_) / 256, 3), 512, 0, stream>>>(
        xh, wqh, wkh, wvh, qh, kh, vth);

    flash_mfma<<<dim3(B_ * H_, 8, 1), 512, 0, stream>>>(qh, kh, vth, oh);

    gemm_wo<<<dim3(D_ / 128, (B_ * T_) / 128, 1), 256, 0, stream>>>(oh, woh, out);
}

// Round 2
// 283.292 us; speedup vs baseline: 1.0212x; 1.0212x over previous
//
#include <hip/hip_runtime.h>
#include <hip/hip_bf16.h>
#include <math.h>

#define B_ 4
#define T_ 2048
#define D_ 1024
#define H_ 16
#define HD_ 64

typedef _Float16 f16x8 __attribute__((ext_vector_type(8)));
typedef _Float16 f16x4 __attribute__((ext_vector_type(4)));
typedef float f32x4 __attribute__((ext_vector_type(4)));

// async global->LDS, 16 B per lane, dest = wave-uniform base + lane*16
__device__ __forceinline__ void gload_lds16(const _Float16* g, _Float16* l) {
    __builtin_amdgcn_global_load_lds(
        (const __attribute__((address_space(1))) void*)g,
        (__attribute__((address_space(3))) void*)l,
        16, 0, 0);
}

// ---------------------------------------------------------------------------
// fp32 -> fp16 cast, 4 elems/thread
// ---------------------------------------------------------------------------
__global__ __launch_bounds__(256) void castf(const float* __restrict__ in,
                                             _Float16* __restrict__ out, int n4) {
    const int i = blockIdx.x * 256 + threadIdx.x;
    if (i < n4) {
        const float4 v = ((const float4*)in)[i];
        f16x4 h = {(_Float16)v.x, (_Float16)v.y, (_Float16)v.z, (_Float16)v.w};
        ((f16x4*)out)[i] = h;
    }
}

// fused 4-weight cast: grid.z selects which weight
__global__ __launch_bounds__(256) void castw(const float* __restrict__ a,
                                             const float* __restrict__ b,
                                             const float* __restrict__ c,
                                             const float* __restrict__ d,
                                             _Float16* __restrict__ oa,
                                             _Float16* __restrict__ ob,
                                             _Float16* __restrict__ oc,
                                             _Float16* __restrict__ od) {
    const int z = blockIdx.z;
    const float* in = (z == 0) ? a : (z == 1 ? b : (z == 2 ? c : d));
    _Float16* out = (z == 0) ? oa : (z == 1 ? ob : (z == 2 ? oc : od));
    const int i = blockIdx.x * 256 + threadIdx.x;
    const float4 v = ((const float4*)in)[i];
    f16x4 h = {(_Float16)v.x, (_Float16)v.y, (_Float16)v.z, (_Float16)v.w};
    ((f16x4*)out)[i] = h;
}

// ---------------------------------------------------------------------------
// Fused QKV GEMM + rmsnorm/rotary epilogue — 256x256 8-phase template
// (T2 swizzle + T3/T4 counted vmcnt + T5 setprio).
// ROUND 2 FIX: deepest-legal staging assignment -> vmcnt(6) (3 half-tile
// units in flight, template-exact), min issue->wait distance 3 phases.
// Staging slots (earliest phase whose preceding barrier frees the region):
//   p1: B1h1(t=2i+1)   p3: A0h0(t=2i+2)   p4: A0h1 + B0h0   p5: B0h1
//   p7: A1h0(t=2i+3)   p8: A1h1 + B1h0
// Issue order: [a1h0' a1h1' b1h0'] b1h1 a0h0 a0h1 b0h0 |D1 vmcnt(6)|
//              b0h1 a1h0 a1h1 b1h0 |D2 vmcnt(6)|
// D1 retires buf1 tile(2i+1) fully (incl b1h1) before p5; leaves buf0-next
// 3 units. D2 retires buf0 tile(2i+2) fully before next p1; leaves buf1-next
// 3 units. Collective guarantee via drain+barrier (all threads same order).
// z=0: rms+rotary+0.125*log2e -> qh ; z=1: rms+rotary -> kh ;
// z=2: plain -> vt transposed [b][h][d][T]
// ---------------------------------------------------------------------------

#define PHASE_MID() \
    __builtin_amdgcn_s_barrier(); \
    asm volatile("s_waitcnt lgkmcnt(0)" ::: "memory"); \
    __builtin_amdgcn_sched_barrier(0); \
    __builtin_amdgcn_s_setprio(1)

#define PHASE_END() \
    __builtin_amdgcn_s_setprio(0); \
    __builtin_amdgcn_s_barrier()

#define VM_PHASE_END(N) \
    __builtin_amdgcn_s_setprio(0); \
    __builtin_amdgcn_sched_barrier(0); \
    asm volatile("s_waitcnt vmcnt(" #N ")" ::: "memory"); \
    __builtin_amdgcn_sched_barrier(0); \
    __builtin_amdgcn_s_barrier()

#define LOAD_A(AR, P, MH) { \
    _Pragma("unroll") \
    for (int i_ = 0; i_ < 4; ++i_) { \
        AR[i_][0] = *(const f16x8*)&As[(P) * 16384 + rowA[MH][i_] + c0s]; \
        AR[i_][1] = *(const f16x8*)&As[(P) * 16384 + rowA[MH][i_] + c1s]; \
    } }

#define LOAD_B(P, NH) { \
    _Pragma("unroll") \
    for (int j_ = 0; j_ < 2; ++j_) { \
        bF[j_][0] = *(const f16x8*)&Bs[(P) * 16384 + rowB[2 * (NH) + j_] + c0s]; \
        bF[j_][1] = *(const f16x8*)&Bs[(P) * 16384 + rowB[2 * (NH) + j_] + c1s]; \
    } }

#define MFMA_Q(AR, MB, NH) { \
    _Pragma("unroll") \
    for (int i_ = 0; i_ < 4; ++i_) { \
        _Pragma("unroll") \
        for (int j_ = 0; j_ < 2; ++j_) { \
            f32x4& d_ = acc[(MB) + i_][2 * (NH) + j_]; \
            d_ = __builtin_amdgcn_mfma_f32_16x16x32_f16(AR[i_][0], bF[j_][0], d_, 0, 0, 0); \
            d_ = __builtin_amdgcn_mfma_f32_16x16x32_f16(AR[i_][1], bF[j_][1], d_, 0, 0, 0); \
        } } }

#define STAGE_A(P, T, HH) \
    gload_lds16(Ap + (size_t)(row0 + (HH) * 128 + w8s) * 1024 + (T) * 64 + sch, \
                &As[(P) * 16384 + (HH) * 8192 + (w << 9)]); \
    gload_lds16(Ap + (size_t)(row0 + (HH) * 128 + 64 + w8s) * 1024 + (T) * 64 + sch, \
                &As[(P) * 16384 + (HH) * 8192 + 4096 + (w << 9)])

#define STAGE_B(P, T, HH) \
    gload_lds16(Wp + (size_t)(col0 + (HH) * 128 + w8s) * 1024 + (T) * 64 + sch, \
                &Bs[(P) * 16384 + (HH) * 8192 + (w << 9)]); \
    gload_lds16(Wp + (size_t)(col0 + (HH) * 128 + 64 + w8s) * 1024 + (T) * 64 + sch, \
                &Bs[(P) * 16384 + (HH) * 8192 + 4096 + (w << 9)])

__global__ __launch_bounds__(512, 2) void gemm_qkv(const _Float16* __restrict__ A,
                                                   const _Float16* __restrict__ Wq,
                                                   const _Float16* __restrict__ Wk,
                                                   const _Float16* __restrict__ Wv,
                                                   _Float16* __restrict__ qh,
                                                   _Float16* __restrict__ kh,
                                                   _Float16* __restrict__ vt) {
    const int z = blockIdx.z;
    const _Float16* Wp = (z == 0) ? Wq : (z == 1 ? Wk : Wv);
    const _Float16* Ap = A;
    __shared__ _Float16 As[2 * 16384];   // 2 bufs x 256 rows x 64 cols
    __shared__ _Float16 Bs[2 * 16384];

    const int tid = threadIdx.x;
    const int lane = tid & 63, w = tid >> 6;          // 8 waves
    const int col = lane & 15, quad = lane >> 4;
    const int wr = w >> 2, wc = w & 3;                // 2M x 4N wave grid
    const int row0 = blockIdx.y * 256, col0 = blockIdx.x * 256;

    // staging per-lane constants (pre-swizzled global source, linear LDS dest)
    const int w8s = (w << 3) + (lane >> 3);
    const int sch = (((lane & 7) ^ (lane >> 3)) << 3);

    // ds_read addressing: logical chunk (quad | 4*ks) at physical chunk ^ (row&7)
    const int swz = col & 7;
    const int c0s = ((quad ^ swz) << 3);
    const int c1s = (((quad | 4) ^ swz) << 3);

    int rowA[2][4], rowB[4];
#pragma unroll
    for (int i = 0; i < 4; ++i) {
        rowA[0][i] = (wr * 128 + i * 16 + col) * 64;
        rowA[1][i] = rowA[0][i] + 4096;
        rowB[i]    = (wc * 64 + i * 16 + col) * 64;
    }

    f32x4 acc[8][4];
#pragma unroll
    for (int i = 0; i < 8; ++i)
#pragma unroll
        for (int j = 0; j < 4; ++j) acc[i][j] = (f32x4){0.f, 0.f, 0.f, 0.f};

    f16x8 aF[4][2], aG[4][2], bF[2][2];

    // ---- prologue: t0 full -> buf0, t1 A both halves + B h0 -> buf1 ----
    // 7 units issued; vmcnt(6)=3 units left = {a1h0,a1h1,b1h0} (t1) —
    // exactly the steady-state entry condition of p1.
    STAGE_A(0, 0, 0); STAGE_A(0, 0, 1);
    STAGE_B(0, 0, 0); STAGE_B(0, 0, 1);
    STAGE_A(1, 1, 0); STAGE_A(1, 1, 1);
    STAGE_B(1, 1, 0);
    __builtin_amdgcn_sched_barrier(0);
    asm volatile("s_waitcnt vmcnt(6)" ::: "memory");
    __builtin_amdgcn_sched_barrier(0);
    __builtin_amdgcn_s_barrier();

    // ---- main loop: 7 iters x 2 K-tiles (tiles 0..13) ----
    for (int it = 0; it < 7; ++it) {
        const int c1 = 2 * it + 1, n0 = 2 * it + 2, n1 = 2 * it + 3;
        // p1  (buf1.B free since prev p8 barrier -> stage its h1)
        LOAD_A(aF, 0, 0); LOAD_B(0, 0);
        STAGE_B(1, c1, 1);
        PHASE_MID(); MFMA_Q(aF, 0, 0); PHASE_END();
        // p2
        LOAD_A(aG, 0, 1);
        PHASE_MID(); MFMA_Q(aG, 4, 0); PHASE_END();
        // p3  (buf0.A free after p2 barrier)
        LOAD_B(0, 1);
        STAGE_A(0, n0, 0);
        PHASE_MID(); MFMA_Q(aG, 4, 1); PHASE_END();
        // p4  (buf0.B free after p3 barrier)
        STAGE_A(0, n0, 1);
        STAGE_B(0, n0, 0);
        PHASE_MID(); MFMA_Q(aF, 0, 1);
        VM_PHASE_END(6);
        // p5
        LOAD_A(aF, 1, 0); LOAD_B(1, 0);
        STAGE_B(0, n0, 1);
        PHASE_MID(); MFMA_Q(aF, 0, 0); PHASE_END();
        // p6
        LOAD_A(aG, 1, 1);
        PHASE_MID(); MFMA_Q(aG, 4, 0); PHASE_END();
        // p7  (buf1.A free after p6 barrier)
        LOAD_B(1, 1);
        STAGE_A(1, n1, 0);
        PHASE_MID(); MFMA_Q(aG, 4, 1); PHASE_END();
        // p8  (buf1.B free after p7 barrier)
        STAGE_A(1, n1, 1);
        STAGE_B(1, n1, 0);
        PHASE_MID(); MFMA_Q(aF, 0, 1);
        VM_PHASE_END(6);
    }

    // ---- epilogue iter: tiles 14 (buf0), 15 (buf1); only t15.Bh1 to stage
    // p1
    LOAD_A(aF, 0, 0); LOAD_B(0, 0);
    STAGE_B(1, 15, 1);
    PHASE_MID(); MFMA_Q(aF, 0, 0); PHASE_END();
    // p2
    LOAD_A(aG, 0, 1);
    PHASE_MID(); MFMA_Q(aG, 4, 0); PHASE_END();
    // p3
    LOAD_B(0, 1);
    PHASE_MID(); MFMA_Q(aG, 4, 1); PHASE_END();
    // p4 — drain: all of t15 (4 units outstanding) must land before p5
    PHASE_MID(); MFMA_Q(aF, 0, 1);
    VM_PHASE_END(0);
    // p5
    LOAD_A(aF, 1, 0); LOAD_B(1, 0);
    PHASE_MID(); MFMA_Q(aF, 0, 0); PHASE_END();
    // p6
    LOAD_A(aG, 1, 1);
    PHASE_MID(); MFMA_Q(aG, 4, 0); PHASE_END();
    // p7
    LOAD_B(1, 1);
    PHASE_MID(); MFMA_Q(aG, 4, 1); PHASE_END();
    // p8 (no trailing barrier needed; epilogue is reg/global only)
    PHASE_MID(); MFMA_Q(aF, 0, 1);
    __builtin_amdgcn_s_setprio(0);

    // ---- C epilogue ----
    if (z < 2) {
        _Float16* C = (z == 0) ? qh : kh;
        const float qscale = (z == 0) ? 0.18033688011112042f : 1.0f;  // 0.125*log2(e)
        const float fr = exp2f(-10.0f * (float)col * (1.0f / 15.0f));
#pragma unroll
        for (int mi = 0; mi < 8; ++mi) {
            float ssq[4];
#pragma unroll
            for (int r = 0; r < 4; ++r) {
                float t = 0.f;
#pragma unroll
                for (int ni = 0; ni < 4; ++ni) t += acc[mi][ni][r] * acc[mi][ni][r];
                ssq[r] = t;
            }
#pragma unroll
            for (int st = 1; st < 16; st <<= 1)
#pragma unroll
                for (int r = 0; r < 4; ++r) ssq[r] += __shfl_xor(ssq[r], st, 64);
            const int rowb = row0 + wr * 128 + mi * 16 + quad * 4;
#pragma unroll
            for (int r = 0; r < 4; ++r) {
                const float scl = rsqrtf(ssq[r] * (1.0f / 64.0f) + 1e-6f) * qscale;
                const int t = (rowb + r) & (T_ - 1);
                float s, c;
                sincosf((float)t * fr, &s, &c);
                const float x0 = acc[mi][0][r] * scl;
                const float x1 = acc[mi][1][r] * scl;
                const float x2 = acc[mi][2][r] * scl;
                const float x3 = acc[mi][3][r] * scl;
                const float y0 = fmaf(x0, c, x2 * s);
                const float y2 = fmaf(x2, c, -x0 * s);
                const size_t base = (size_t)(rowb + r) * D_ + col0 + wc * 64 + col;
                C[base + 0]  = (_Float16)y0;
                C[base + 16] = (_Float16)x1;
                C[base + 32] = (_Float16)y2;
                C[base + 48] = (_Float16)x3;
            }
        }
    } else {
        const int hh = blockIdx.x * 4 + wc;
#pragma unroll
        for (int mi = 0; mi < 8; ++mi) {
            const int row = row0 + wr * 128 + mi * 16 + quad * 4;
            const int bb = row >> 11;
            const int t0m = row & (T_ - 1);
#pragma unroll
            for (int ni = 0; ni < 4; ++ni) {
                const int d = ni * 16 + col;
                f16x4 pk = {(_Float16)acc[mi][ni][0], (_Float16)acc[mi][ni][1],
                            (_Float16)acc[mi][ni][2], (_Float16)acc[mi][ni][3]};
                *(f16x4*)&vt[((size_t)(bb * H_ + hh) * HD_ + d) * T_ + t0m] = pk;
            }
        }
    }
}

// ---------------------------------------------------------------------------
// WO GEMM: out[M,N] = A[M,K] @ W[N,K]^T, fp16 in, fp32 out. m97 structure.
// ---------------------------------------------------------------------------
__global__ __launch_bounds__(256) void gemm_wo(const _Float16* __restrict__ A,
                                               const _Float16* __restrict__ W,
                                               float* __restrict__ C) {
    constexpr int K = D_, N = D_;
    __shared__ _Float16 As[128 * 32];
    __shared__ _Float16 Bs[128 * 32];
    const int tid = threadIdx.x;
    const int lane = tid & 63, w = tid >> 6;
    const int col = lane & 15, quad = lane >> 4;
    const int wm = w >> 1, wn = w & 1;
    const int row0 = blockIdx.y * 128, col0 = blockIdx.x * 128;
    const int sr = lane >> 2, sc = (lane & 3) * 8;

    f32x4 acc[4][4];
#pragma unroll
    for (int i = 0; i < 4; ++i)
#pragma unroll
        for (int j = 0; j < 4; ++j) acc[i][j] = (f32x4){0.f, 0.f, 0.f, 0.f};

    for (int kt = 0; kt < K / 32; ++kt) {
        const int k0 = kt * 32;
#pragma unroll
        for (int it = 0; it < 2; ++it) {
            const int rb = it * 64 + w * 16;
            gload_lds16(A + (size_t)(row0 + rb + sr) * K + k0 + sc, As + rb * 32);
            gload_lds16(W + (size_t)(col0 + rb + sr) * K + k0 + sc, Bs + rb * 32);
        }
        __syncthreads();
        f16x8 af[4], bf[4];
#pragma unroll
        for (int i = 0; i < 4; ++i) {
            af[i] = *(const f16x8*)&As[(wm * 64 + i * 16 + col) * 32 + quad * 8];
            bf[i] = *(const f16x8*)&Bs[(wn * 64 + i * 16 + col) * 32 + quad * 8];
        }
#pragma unroll
        for (int mi = 0; mi < 4; ++mi)
#pragma unroll
            for (int ni = 0; ni < 4; ++ni)
                acc[mi][ni] = __builtin_amdgcn_mfma_f32_16x16x32_f16(af[mi], bf[ni],
                                                                     acc[mi][ni], 0, 0, 0);
        __syncthreads();
    }
#pragma unroll
    for (int mi = 0; mi < 4; ++mi)
#pragma unroll
        for (int ni = 0; ni < 4; ++ni)
#pragma unroll
            for (int r = 0; r < 4; ++r)
                C[(size_t)(row0 + wm * 64 + mi * 16 + quad * 4 + r) * N +
                  col0 + wn * 64 + ni * 16 + col] = acc[mi][ni][r];
}

// ---------------------------------------------------------------------------
// MFMA flash attention (fp16 in/out). 512 thr = 8 waves, 128 q per block,
// wave w owns q rows [q0+16w, q0+16w+16). K-tiles of 64 keys.
// ---------------------------------------------------------------------------
#define LDP 88

__global__ __launch_bounds__(512) void flash_mfma(const _Float16* __restrict__ qh,
                                                  const _Float16* __restrict__ kh,
                                                  const _Float16* __restrict__ vt,
                                                  _Float16* __restrict__ o) {
    __shared__ _Float16 Kl[64 * 64];
    __shared__ _Float16 Vl[64 * 64];
    __shared__ _Float16 Pl[8][16 * LDP];
    const int tid = threadIdx.x;
    const int lane = tid & 63, w = tid >> 6;           // w in [0,8)
    const int col = lane & 15, quad = lane >> 4;
    const int bh = blockIdx.x, b = bh >> 4, h = bh & 15;
    const int srow = lane >> 3;                        // row-in-8 for staging
    const int schunk = (lane & 7) ^ srow;              // global-side swizzle
    const int sw = col & 7;                            // read-side swizzle key

    for (int phase = 0; phase < 2; ++phase) {
        const int qt = (phase == 0) ? (int)blockIdx.y : (15 - (int)blockIdx.y);
        const int q0 = qt * 128;

        // Q as B-operand: lane holds Q[q=q0+16w+col][d = quad*8+j (+32)]
        const int tq = q0 + w * 16 + col;
        const _Float16* qp = qh + ((size_t)(b * T_ + tq) * H_ + h) * HD_ + quad * 8;
        const f16x8 qB0 = *(const f16x8*)(qp);
        const f16x8 qB1 = *(const f16x8*)(qp + 32);

        f32x4 oa[4];
#pragma unroll
        for (int i = 0; i < 4; ++i) oa[i] = (f32x4){0.f, 0.f, 0.f, 0.f};
        float l_ = 0.f;  // per-lane partial denom for q = col

        const int nkt = 2 * qt + 2;
        for (int kt = 0; kt < nkt; ++kt) {
            const int k0 = kt * 64;
            // ---- stage K[key][d], Vt[d][key]: 512 thr x 16 B = full tile ----
            {
                const int r = w * 8 + srow;
                gload_lds16(kh + ((size_t)(b * T_ + k0 + r) * H_ + h) * HD_ + schunk * 8,
                            Kl + (w * 8) * 64);
                gload_lds16(vt + ((size_t)(b * H_ + h) * HD_ + r) * T_ + k0 + schunk * 8,
                            Vl + (w * 8) * 64);
            }
            __syncthreads();

            // ---- S^T[key][q]: A = K rows, B = Q (in regs) ----
            f32x4 s[4];
#pragma unroll
            for (int tn = 0; tn < 4; ++tn) {
                const _Float16* kp = &Kl[(tn * 16 + col) * 64];
                const f16x8 kA0 = *(const f16x8*)(kp + ((quad ^ sw) << 3));
                const f16x8 kA1 = *(const f16x8*)(kp + (((quad | 4) ^ sw) << 3));
                f32x4 a = (f32x4){0.f, 0.f, 0.f, 0.f};
                a = __builtin_amdgcn_mfma_f32_16x16x32_f16(kA0, qB0, a, 0, 0, 0);
                a = __builtin_amdgcn_mfma_f32_16x16x32_f16(kA1, qB1, a, 0, 0, 0);
                s[tn] = a;
            }

            // ---- causal mask: any key in tile beyond this wave's q rows ----
            if (k0 + 63 > q0 + w * 16) {
                const int qq = q0 + w * 16 + col;
#pragma unroll
                for (int tn = 0; tn < 4; ++tn)
#pragma unroll
                    for (int r = 0; r < 4; ++r) {
                        const int key = k0 + tn * 16 + quad * 4 + r;
                        if (key > qq) s[tn][r] = -1e30f;
                    }
            }

            // ---- p = exp2(s); l accumulate; packed P store (4x b64) ----
#pragma unroll
            for (int tn = 0; tn < 4; ++tn) {
                f16x4 pk;
#pragma unroll
                for (int r = 0; r < 4; ++r) {
                    const float p = exp2f(s[tn][r]);
                    l_ += p;
                    pk[r] = (_Float16)p;
                }
                *(f16x4*)&Pl[w][col * LDP + tn * 16 + quad * 4] = pk;
            }

            // ---- O[q][d] += P @ V (Pl[w] wave-private, no barrier) ----
            const f16x8 pA0 = *(const f16x8*)&Pl[w][col * LDP + quad * 8];
            const f16x8 pA1 = *(const f16x8*)&Pl[w][col * LDP + quad * 8 + 32];
#pragma unroll
            for (int tn = 0; tn < 4; ++tn) {
                const _Float16* vp = &Vl[(tn * 16 + col) * 64];
                const f16x8 vB0 = *(const f16x8*)(vp + ((quad ^ sw) << 3));
                const f16x8 vB1 = *(const f16x8*)(vp + (((quad | 4) ^ sw) << 3));
                oa[tn] = __builtin_amdgcn_mfma_f32_16x16x32_f16(pA0, vB0, oa[tn], 0, 0, 0);
                oa[tn] = __builtin_amdgcn_mfma_f32_16x16x32_f16(pA1, vB1, oa[tn], 0, 0, 0);
            }
            __syncthreads();
        }

        // ---- finish l (sum quads), redistribute to O rows, write ----
        l_ += __shfl_xor(l_, 16, 64);
        l_ += __shfl_xor(l_, 32, 64);
        const float linv = 1.0f / l_;
        float inv[4];
#pragma unroll
        for (int r = 0; r < 4; ++r) inv[r] = __shfl(linv, quad * 4 + r, 64);
#pragma unroll
        for (int tn = 0; tn < 4; ++tn)
#pragma unroll
            for (int r = 0; r < 4; ++r)
                o[((size_t)(b * T_ + q0 + w * 16 + quad * 4 + r) * H_ + h) * HD_ + tn * 16 + col] =
                    (_Float16)(oa[tn][r] * inv[r]);
    }
}

// ---------------------------------------------------------------------------
extern "C" void kernel_launch(void* const* d_in, const int* in_sizes, int n_in,
                              void* d_out, int out_size, void* d_ws, size_t ws_size,
                              hipStream_t stream) {
    const float* x  = (const float*)d_in[0];
    const float* wq = (const float*)d_in[1];
    const float* wk = (const float*)d_in[2];
    const float* wv = (const float*)d_in[3];
    const float* wo = (const float*)d_in[4];
    float* out = (float*)d_out;

    const size_t NE = (size_t)B_ * T_ * D_;   // 8,388,608
    const size_t WE = (size_t)D_ * D_;        // 1,048,576
    _Float16* xh  = (_Float16*)d_ws;
    _Float16* qh  = xh + NE;
    _Float16* kh  = qh + NE;
    _Float16* vth = kh + NE;
    _Float16* oh  = vth + NE;
    _Float16* wqh = oh + NE;
    _Float16* wkh = wqh + WE;
    _Float16* wvh = wkh + WE;
    _Float16* woh = wvh + WE;

    castf<<<NE / 1024, 256, 0, stream>>>(x, xh, (int)(NE / 4));
    castw<<<dim3(WE / 1024, 1, 4), 256, 0, stream>>>(wq, wk, wv, wo,
                                                     wqh, wkh, wvh, woh);

    gemm_qkv<<<dim3(D_ / 256, (B_ * T_) / 256, 3), 512, 0, stream>>>(
        xh, wqh, wkh, wvh, qh, kh, vth);

    flash_mfma<<<dim3(B_ * H_, 8, 1), 512, 0, stream>>>(qh, kh, vth, oh);

    gemm_wo<<<dim3(D_ / 128, (B_ * T_) / 128, 1), 256, 0, stream>>>(oh, woh, out);
}

// Round 4
// 275.346 us; speedup vs baseline: 1.0507x; 1.0289x over previous
//
#include <hip/hip_runtime.h>
#include <hip/hip_bf16.h>
#include <math.h>

#define B_ 4
#define T_ 2048
#define D_ 1024
#define H_ 16
#define HD_ 64

typedef _Float16 f16x8 __attribute__((ext_vector_type(8)));
typedef _Float16 f16x4 __attribute__((ext_vector_type(4)));
typedef float f32x4 __attribute__((ext_vector_type(4)));

// async global->LDS, 16 B per lane, dest = wave-uniform base + lane*16
__device__ __forceinline__ void gload_lds16(const _Float16* g, _Float16* l) {
    __builtin_amdgcn_global_load_lds(
        (const __attribute__((address_space(1))) void*)g,
        (__attribute__((address_space(3))) void*)l,
        16, 0, 0);
}

// ---------------------------------------------------------------------------
// fp32 -> fp16 cast, 4 elems/thread
// ---------------------------------------------------------------------------
__global__ __launch_bounds__(256) void castf(const float* __restrict__ in,
                                             _Float16* __restrict__ out, int n4) {
    const int i = blockIdx.x * 256 + threadIdx.x;
    if (i < n4) {
        const float4 v = ((const float4*)in)[i];
        f16x4 h = {(_Float16)v.x, (_Float16)v.y, (_Float16)v.z, (_Float16)v.w};
        ((f16x4*)out)[i] = h;
    }
}

// fused 4-weight cast: grid.z selects which weight
__global__ __launch_bounds__(256) void castw(const float* __restrict__ a,
                                             const float* __restrict__ b,
                                             const float* __restrict__ c,
                                             const float* __restrict__ d,
                                             _Float16* __restrict__ oa,
                                             _Float16* __restrict__ ob,
                                             _Float16* __restrict__ oc,
                                             _Float16* __restrict__ od) {
    const int z = blockIdx.z;
    const float* in = (z == 0) ? a : (z == 1 ? b : (z == 2 ? c : d));
    _Float16* out = (z == 0) ? oa : (z == 1 ? ob : (z == 2 ? oc : od));
    const int i = blockIdx.x * 256 + threadIdx.x;
    const float4 v = ((const float4*)in)[i];
    f16x4 h = {(_Float16)v.x, (_Float16)v.y, (_Float16)v.z, (_Float16)v.w};
    ((f16x4*)out)[i] = h;
}

// ---------------------------------------------------------------------------
// Fused QKV GEMM + rmsnorm/rotary epilogue (m97 structure — REVERTED: the
// 256^2 8-phase port measured 94-97us vs this version's 80.5us at K=1024;
// 1 block/CU + short K-loop don't amortize the deep pipeline).
// z=0: rms+rotary+0.125*log2e -> qh ; z=1: rms+rotary -> kh ;
// z=2: plain -> vt transposed [b][h][d][T]
// ---------------------------------------------------------------------------
__global__ __launch_bounds__(256) void gemm_qkv(const _Float16* __restrict__ A,
                                                const _Float16* __restrict__ Wq,
                                                const _Float16* __restrict__ Wk,
                                                const _Float16* __restrict__ Wv,
                                                _Float16* __restrict__ qh,
                                                _Float16* __restrict__ kh,
                                                _Float16* __restrict__ vt) {
    constexpr int K = D_;
    const int z = blockIdx.z;
    const _Float16* W = (z == 0) ? Wq : (z == 1 ? Wk : Wv);
    __shared__ _Float16 As[128 * 32];
    __shared__ _Float16 Bs[128 * 32];
    const int tid = threadIdx.x;
    const int lane = tid & 63, w = tid >> 6;
    const int col = lane & 15, quad = lane >> 4;
    const int wm = w >> 1, wn = w & 1;
    const int row0 = blockIdx.y * 128, col0 = blockIdx.x * 128;
    const int sr = lane >> 2, sc = (lane & 3) * 8;

    f32x4 acc[4][4];
#pragma unroll
    for (int i = 0; i < 4; ++i)
#pragma unroll
        for (int j = 0; j < 4; ++j) acc[i][j] = (f32x4){0.f, 0.f, 0.f, 0.f};

    for (int kt = 0; kt < K / 32; ++kt) {
        const int k0 = kt * 32;
#pragma unroll
        for (int it = 0; it < 2; ++it) {
            const int rb = it * 64 + w * 16;
            gload_lds16(A + (size_t)(row0 + rb + sr) * K + k0 + sc, As + rb * 32);
            gload_lds16(W + (size_t)(col0 + rb + sr) * K + k0 + sc, Bs + rb * 32);
        }
        __syncthreads();
        f16x8 af[4], bf[4];
#pragma unroll
        for (int i = 0; i < 4; ++i) {
            af[i] = *(const f16x8*)&As[(wm * 64 + i * 16 + col) * 32 + quad * 8];
            bf[i] = *(const f16x8*)&Bs[(wn * 64 + i * 16 + col) * 32 + quad * 8];
        }
#pragma unroll
        for (int mi = 0; mi < 4; ++mi)
#pragma unroll
            for (int ni = 0; ni < 4; ++ni)
                acc[mi][ni] = __builtin_amdgcn_mfma_f32_16x16x32_f16(af[mi], bf[ni],
                                                                     acc[mi][ni], 0, 0, 0);
        __syncthreads();
    }

    if (z < 2) {
        _Float16* C = (z == 0) ? qh : kh;
        const float qscale = (z == 0) ? 0.18033688011112042f : 1.0f;  // 0.125*log2(e)
        const float fr = exp2f(-10.0f * (float)col * (1.0f / 15.0f));
#pragma unroll
        for (int mi = 0; mi < 4; ++mi) {
            float ssq[4];
#pragma unroll
            for (int r = 0; r < 4; ++r) {
                float t = 0.f;
#pragma unroll
                for (int ni = 0; ni < 4; ++ni) t += acc[mi][ni][r] * acc[mi][ni][r];
                ssq[r] = t;
            }
#pragma unroll
            for (int st = 1; st < 16; st <<= 1)
#pragma unroll
                for (int r = 0; r < 4; ++r) ssq[r] += __shfl_xor(ssq[r], st, 64);
            const int rowb = row0 + wm * 64 + mi * 16 + quad * 4;
#pragma unroll
            for (int r = 0; r < 4; ++r) {
                const float scl = rsqrtf(ssq[r] * (1.0f / 64.0f) + 1e-6f) * qscale;
                const int t = (rowb + r) & (T_ - 1);
                float s, c;
                sincosf((float)t * fr, &s, &c);
                const float x0 = acc[mi][0][r] * scl;
                const float x1 = acc[mi][1][r] * scl;
                const float x2 = acc[mi][2][r] * scl;
                const float x3 = acc[mi][3][r] * scl;
                const float y0 = fmaf(x0, c, x2 * s);
                const float y2 = fmaf(x2, c, -x0 * s);
                const size_t base = (size_t)(rowb + r) * D_ + col0 + wn * 64 + col;
                C[base + 0]  = (_Float16)y0;
                C[base + 16] = (_Float16)x1;
                C[base + 32] = (_Float16)y2;
                C[base + 48] = (_Float16)x3;
            }
        }
    } else {
        const int hh = blockIdx.x * 2 + wn;
#pragma unroll
        for (int mi = 0; mi < 4; ++mi) {
            const int row = row0 + wm * 64 + mi * 16 + quad * 4;
            const int bb = row >> 11;
            const int t0m = row & (T_ - 1);
#pragma unroll
            for (int ni = 0; ni < 4; ++ni) {
                const int d = ni * 16 + col;
                f16x4 pk = {(_Float16)acc[mi][ni][0], (_Float16)acc[mi][ni][1],
                            (_Float16)acc[mi][ni][2], (_Float16)acc[mi][ni][3]};
                *(f16x4*)&vt[((size_t)(bb * H_ + hh) * HD_ + d) * T_ + t0m] = pk;
            }
        }
    }
}

// ---------------------------------------------------------------------------
// WO GEMM: out[M,N] = A[M,K] @ W[N,K]^T, fp16 in, fp32 out. m97 structure.
// ---------------------------------------------------------------------------
__global__ __launch_bounds__(256) void gemm_wo(const _Float16* __restrict__ A,
                                               const _Float16* __restrict__ W,
                                               float* __restrict__ C) {
    constexpr int K = D_, N = D_;
    __shared__ _Float16 As[128 * 32];
    __shared__ _Float16 Bs[128 * 32];
    const int tid = threadIdx.x;
    const int lane = tid & 63, w = tid >> 6;
    const int col = lane & 15, quad = lane >> 4;
    const int wm = w >> 1, wn = w & 1;
    const int row0 = blockIdx.y * 128, col0 = blockIdx.x * 128;
    const int sr = lane >> 2, sc = (lane & 3) * 8;

    f32x4 acc[4][4];
#pragma unroll
    for (int i = 0; i < 4; ++i)
#pragma unroll
        for (int j = 0; j < 4; ++j) acc[i][j] = (f32x4){0.f, 0.f, 0.f, 0.f};

    for (int kt = 0; kt < K / 32; ++kt) {
        const int k0 = kt * 32;
#pragma unroll
        for (int it = 0; it < 2; ++it) {
            const int rb = it * 64 + w * 16;
            gload_lds16(A + (size_t)(row0 + rb + sr) * K + k0 + sc, As + rb * 32);
            gload_lds16(W + (size_t)(col0 + rb + sr) * K + k0 + sc, Bs + rb * 32);
        }
        __syncthreads();
        f16x8 af[4], bf[4];
#pragma unroll
        for (int i = 0; i < 4; ++i) {
            af[i] = *(const f16x8*)&As[(wm * 64 + i * 16 + col) * 32 + quad * 8];
            bf[i] = *(const f16x8*)&Bs[(wn * 64 + i * 16 + col) * 32 + quad * 8];
        }
#pragma unroll
        for (int mi = 0; mi < 4; ++mi)
#pragma unroll
            for (int ni = 0; ni < 4; ++ni)
                acc[mi][ni] = __builtin_amdgcn_mfma_f32_16x16x32_f16(af[mi], bf[ni],
                                                                     acc[mi][ni], 0, 0, 0);
        __syncthreads();
    }
#pragma unroll
    for (int mi = 0; mi < 4; ++mi)
#pragma unroll
        for (int ni = 0; ni < 4; ++ni)
#pragma unroll
            for (int r = 0; r < 4; ++r)
                C[(size_t)(row0 + wm * 64 + mi * 16 + quad * 4 + r) * N +
                  col0 + wn * 64 + ni * 16 + col] = acc[mi][ni][r];
}

// ---------------------------------------------------------------------------
// MFMA flash attention (fp16 in/out). 512 thr = 8 waves, 128 q per block,
// wave w owns q rows [q0+16w, q0+16w+16). K-tiles of 64 keys.
// ROUND 3 (resubmit; round-3 bench was an infra failure, no signal):
// double-buffered K/V staging (T3 minimum 2-phase). Stage tile kt+1 ->
// buf[cur^1] at iteration top; compute tile kt from buf[cur]; single
// vmcnt(0)+s_barrier per tile at iteration end (was 2x full-drain
// __syncthreads). Pl stays wave-private (no cross-wave lgkm) so a raw
// s_barrier + explicit vmcnt drain is sufficient; sched_barrier(0) fences
// around the asm waits (rule #18). T5 setprio around MFMA clusters.
// Buffer safety: iter kt stages buf[(kt+1)&1], last read in iter kt-1;
// the end-of-(kt-1) barrier orders that read before this write.
// ---------------------------------------------------------------------------
#define LDP 88

__global__ __launch_bounds__(512) void flash_mfma(const _Float16* __restrict__ qh,
                                                  const _Float16* __restrict__ kh,
                                                  const _Float16* __restrict__ vt,
                                                  _Float16* __restrict__ o) {
    __shared__ _Float16 Kl[2][64 * 64];
    __shared__ _Float16 Vl[2][64 * 64];
    __shared__ _Float16 Pl[8][16 * LDP];
    const int tid = threadIdx.x;
    const int lane = tid & 63, w = tid >> 6;           // w in [0,8)
    const int col = lane & 15, quad = lane >> 4;
    const int bh = blockIdx.x, b = bh >> 4, h = bh & 15;
    const int srow = lane >> 3;                        // row-in-8 for staging
    const int schunk = (lane & 7) ^ srow;              // global-side swizzle
    const int sw = col & 7;                            // read-side swizzle key
    const int rstg = w * 8 + srow;                     // staged row (0..63)

    const _Float16* kbase = kh + ((size_t)b * T_ * H_ + (size_t)h) * HD_;
    const _Float16* vbase = vt + ((size_t)(b * H_ + h)) * (size_t)HD_ * T_;

    for (int phase = 0; phase < 2; ++phase) {
        const int qt = (phase == 0) ? (int)blockIdx.y : (15 - (int)blockIdx.y);
        const int q0 = qt * 128;

        // Q as B-operand: lane holds Q[q=q0+16w+col][d = quad*8+j (+32)]
        const int tq = q0 + w * 16 + col;
        const _Float16* qp = qh + ((size_t)(b * T_ + tq) * H_ + h) * HD_ + quad * 8;
        const f16x8 qB0 = *(const f16x8*)(qp);
        const f16x8 qB1 = *(const f16x8*)(qp + 32);

        f32x4 oa[4];
#pragma unroll
        for (int i = 0; i < 4; ++i) oa[i] = (f32x4){0.f, 0.f, 0.f, 0.f};
        float l_ = 0.f;  // per-lane partial denom for q = col

        const int nkt = 2 * qt + 2;

        // ---- prologue: stage tile 0 -> buf 0, full drain ----
        gload_lds16(kbase + (size_t)(0 + rstg) * H_ * HD_ + schunk * 8,
                    &Kl[0][(w * 8) * 64]);
        gload_lds16(vbase + (size_t)rstg * T_ + 0 + schunk * 8,
                    &Vl[0][(w * 8) * 64]);
        __builtin_amdgcn_sched_barrier(0);
        asm volatile("s_waitcnt vmcnt(0)" ::: "memory");
        __builtin_amdgcn_sched_barrier(0);
        __builtin_amdgcn_s_barrier();

        for (int kt = 0; kt < nkt; ++kt) {
            const int k0 = kt * 64;
            const int cur = kt & 1;

            // ---- issue next tile's stage early (hides under compute) ----
            if (kt + 1 < nkt) {
                gload_lds16(kbase + (size_t)(k0 + 64 + rstg) * H_ * HD_ + schunk * 8,
                            &Kl[cur ^ 1][(w * 8) * 64]);
                gload_lds16(vbase + (size_t)rstg * T_ + k0 + 64 + schunk * 8,
                            &Vl[cur ^ 1][(w * 8) * 64]);
            }

            // ---- S^T[key][q]: A = K rows, B = Q (in regs) ----
            f32x4 s[4];
            __builtin_amdgcn_s_setprio(1);
#pragma unroll
            for (int tn = 0; tn < 4; ++tn) {
                const _Float16* kp = &Kl[cur][(tn * 16 + col) * 64];
                const f16x8 kA0 = *(const f16x8*)(kp + ((quad ^ sw) << 3));
                const f16x8 kA1 = *(const f16x8*)(kp + (((quad | 4) ^ sw) << 3));
                f32x4 a = (f32x4){0.f, 0.f, 0.f, 0.f};
                a = __builtin_amdgcn_mfma_f32_16x16x32_f16(kA0, qB0, a, 0, 0, 0);
                a = __builtin_amdgcn_mfma_f32_16x16x32_f16(kA1, qB1, a, 0, 0, 0);
                s[tn] = a;
            }
            __builtin_amdgcn_s_setprio(0);

            // ---- causal mask: any key in tile beyond this wave's q rows ----
            if (k0 + 63 > q0 + w * 16) {
                const int qq = q0 + w * 16 + col;
#pragma unroll
                for (int tn = 0; tn < 4; ++tn)
#pragma unroll
                    for (int r = 0; r < 4; ++r) {
                        const int key = k0 + tn * 16 + quad * 4 + r;
                        if (key > qq) s[tn][r] = -1e30f;
                    }
            }

            // ---- p = exp2(s); l accumulate; packed P store (4x b64) ----
#pragma unroll
            for (int tn = 0; tn < 4; ++tn) {
                f16x4 pk;
#pragma unroll
                for (int r = 0; r < 4; ++r) {
                    const float p = exp2f(s[tn][r]);
                    l_ += p;
                    pk[r] = (_Float16)p;
                }
                *(f16x4*)&Pl[w][col * LDP + tn * 16 + quad * 4] = pk;
            }

            // ---- O[q][d] += P @ V (Pl[w] wave-private, no barrier) ----
            const f16x8 pA0 = *(const f16x8*)&Pl[w][col * LDP + quad * 8];
            const f16x8 pA1 = *(const f16x8*)&Pl[w][col * LDP + quad * 8 + 32];
            __builtin_amdgcn_s_setprio(1);
#pragma unroll
            for (int tn = 0; tn < 4; ++tn) {
                const _Float16* vp = &Vl[cur][(tn * 16 + col) * 64];
                const f16x8 vB0 = *(const f16x8*)(vp + ((quad ^ sw) << 3));
                const f16x8 vB1 = *(const f16x8*)(vp + (((quad | 4) ^ sw) << 3));
                oa[tn] = __builtin_amdgcn_mfma_f32_16x16x32_f16(pA0, vB0, oa[tn], 0, 0, 0);
                oa[tn] = __builtin_amdgcn_mfma_f32_16x16x32_f16(pA1, vB1, oa[tn], 0, 0, 0);
            }
            __builtin_amdgcn_s_setprio(0);

            // ---- single per-tile sync: next tile landed + all waves done ----
            __builtin_amdgcn_sched_barrier(0);
            asm volatile("s_waitcnt vmcnt(0)" ::: "memory");
            __builtin_amdgcn_sched_barrier(0);
            __builtin_amdgcn_s_barrier();
        }

        // ---- finish l (sum quads), redistribute to O rows, write ----
        l_ += __shfl_xor(l_, 16, 64);
        l_ += __shfl_xor(l_, 32, 64);
        const float linv = 1.0f / l_;
        float inv[4];
#pragma unroll
        for (int r = 0; r < 4; ++r) inv[r] = __shfl(linv, quad * 4 + r, 64);
#pragma unroll
        for (int tn = 0; tn < 4; ++tn)
#pragma unroll
            for (int r = 0; r < 4; ++r)
                o[((size_t)(b * T_ + q0 + w * 16 + quad * 4 + r) * H_ + h) * HD_ + tn * 16 + col] =
                    (_Float16)(oa[tn][r] * inv[r]);
    }
}

// ---------------------------------------------------------------------------
extern "C" void kernel_launch(void* const* d_in, const int* in_sizes, int n_in,
                              void* d_out, int out_size, void* d_ws, size_t ws_size,
                              hipStream_t stream) {
    const float* x  = (const float*)d_in[0];
    const float* wq = (const float*)d_in[1];
    const float* wk = (const float*)d_in[2];
    const float* wv = (const float*)d_in[3];
    const float* wo = (const float*)d_in[4];
    float* out = (float*)d_out;

    const size_t NE = (size_t)B_ * T_ * D_;   // 8,388,608
    const size_t WE = (size_t)D_ * D_;        // 1,048,576
    _Float16* xh  = (_Float16*)d_ws;
    _Float16* qh  = xh + NE;
    _Float16* kh  = qh + NE;
    _Float16* vth = kh + NE;
    _Float16* oh  = vth + NE;
    _Float16* wqh = oh + NE;
    _Float16* wkh = wqh + WE;
    _Float16* wvh = wkh + WE;
    _Float16* woh = wvh + WE;

    castf<<<NE / 1024, 256, 0, stream>>>(x, xh, (int)(NE / 4));
    castw<<<dim3(WE / 1024, 1, 4), 256, 0, stream>>>(wq, wk, wv, wo,
                                                     wqh, wkh, wvh, woh);

    gemm_qkv<<<dim3(D_ / 128, (B_ * T_) / 128, 3), 256, 0, stream>>>(
        xh, wqh, wkh, wvh, qh, kh, vth);

    flash_mfma<<<dim3(B_ * H_, 8, 1), 512, 0, stream>>>(qh, kh, vth, oh);

    gemm_wo<<<dim3(D_ / 128, (B_ * T_) / 128, 1), 256, 0, stream>>>(oh, woh, out);
}